// Round 5
// baseline (3268.106 us; speedup 1.0000x reference)
//
#include <hip/hip_runtime.h>
#include <math.h>

#define NX 192
#define NY 192
#define NZ 96
#define NV 4
#define VOL (NZ * NY * NX)      /* 3,538,944 */
#define NTOT (NV * VOL)         /* 14,155,776 */
#define VOL4 (VOL / 4)
#define NTOT4 (NTOT / 4)
#define YS NX
#define ZS (NY * NX)

#define TX 48
#define TY 16
#define ZCH 24
#define NG 14
#define NGP 15
#define AROWS (TY + 4)
#define EROWS (TY + 2)
#define AJOBS (AROWS * NG)
#define EJOBS (EROWS * NG)
#define UJOBS (TY * (TX / 4))
#define RA 22
#define RE1 20
#define RE2 18

__device__ __forceinline__ float4 min4(float4 a, float4 b) {
    return make_float4(fminf(a.x, b.x), fminf(a.y, b.y),
                       fminf(a.z, b.z), fminf(a.w, b.w));
}
__device__ __forceinline__ float4 max4(float4 a, float4 b) {
    return make_float4(fmaxf(a.x, b.x), fmaxf(a.y, b.y),
                       fmaxf(a.z, b.z), fmaxf(a.w, b.w));
}
__device__ __forceinline__ float4 win3max(float a, float4 b, float c) {
    return make_float4(fmaxf(fmaxf(a, b.x), b.y),
                       fmaxf(fmaxf(b.x, b.y), b.z),
                       fmaxf(fmaxf(b.y, b.z), b.w),
                       fmaxf(fmaxf(b.z, b.w), c));
}

__global__ void extract_kernel(const float* __restrict__ pred,
                               const float* __restrict__ target,
                               float* __restrict__ cur) {
    int i = blockIdx.x * blockDim.x + threadIdx.x;
    if (i >= NTOT4) return;
    int v = i / VOL4;
    int p = i - v * VOL4;
    int b = v & 1;
    const float4* src = (const float4*)((v < 2) ? pred : target);
    ((float4*)cur)[i] = src[(size_t)(b * 2 + 1) * VOL4 + p];
}

// ---------------- single-round kernel (round 0) — verified ----------------
__global__ __launch_bounds__(256, 3) void fused_kernel(const float* __restrict__ A,
                                                       float* __restrict__ E,
                                                       float* __restrict__ skel) {
    __shared__ float4 As[4][AROWS][NG];
    __shared__ float4 Es[3][EROWS][NG];
    __shared__ float4 Ms[EROWS][NG];

    const int tid = threadIdx.x;
    const int x0 = blockIdx.x * TX;
    const int y0 = blockIdx.y * TY;
    const int v  = blockIdx.z >> 2;
    const int z0 = (blockIdx.z & 3) * ZCH;
    const int z1 = z0 + ZCH;

    const float* Av = A + (size_t)v * VOL;
    float* Ev = E + (size_t)v * VOL;
    float* Sv = skel + (size_t)v * VOL;

    const float4 PINF4 = make_float4(INFINITY, INFINITY, INFINITY, INFINITY);
    const float4 NINF4 = make_float4(-INFINITY, -INFINITY, -INFINITY, -INFINITY);

    auto stageA = [&](int z) {
        int slot = (z + 8) & 3;
        float4* dst = &As[slot][0][0];
        if (z < 0 || z >= NZ) {
            for (int j = tid; j < AJOBS; j += 256) dst[j] = PINF4;
        } else {
            const float* P = Av + (size_t)z * ZS;
            for (int j = tid; j < AJOBS; j += 256) {
                int r = j / NG, g = j - r * NG;
                int gy = y0 - 2 + r;
                int gx0 = x0 - 4 + 4 * g;
                float4 val = PINF4;
                if (gy >= 0 && gy < NY && gx0 >= 0 && gx0 < NX)
                    val = *(const float4*)(P + gy * YS + gx0);
                dst[j] = val;
            }
        }
    };

    auto eplane = [&](int z) {
        int es = (z + 9) % 3;
        float4* dst = &Es[es][0][0];
        if (z < 0 || z >= NZ) {
            for (int j = tid; j < EJOBS; j += 256) dst[j] = NINF4;
            return;
        }
        const int sc = (z + 8) & 3;
        const int sm = (z + 7) & 3;
        const int sp = (z + 9) & 3;
        const bool wr = (z >= z0 && z < z1);
        for (int j = tid; j < EJOBS; j += 256) {
            int r = j / NG, g = j - r * NG;
            float4 c  = As[sc][r + 1][g];
            float4 yl = As[sc][r][g];
            float4 yh = As[sc][r + 2][g];
            float4 zl = As[sm][r + 1][g];
            float4 zh = As[sp][r + 1][g];
            float pw = (g > 0)      ? As[sc][r + 1][g - 1].w : INFINITY;
            float nx = (g < NG - 1) ? As[sc][r + 1][g + 1].x : INFINITY;
            float4 xl = make_float4(pw, c.x, c.y, c.z);
            float4 xr = make_float4(c.y, c.z, c.w, nx);
            float4 m = min4(c, xl);
            m = min4(m, xr);
            m = min4(m, yl);
            m = min4(m, yh);
            m = min4(m, zl);
            m = min4(m, zh);
            int gy = y0 - 1 + r;
            int gx0 = x0 - 4 + 4 * g;
            if (gy < 0 || gy >= NY || gx0 < 0 || gx0 >= NX) m = NINF4;
            dst[j] = m;
            if (wr && r >= 1 && r <= TY && g >= 1 && g <= NG - 2)
                *(float4*)(Ev + (size_t)z * ZS + gy * YS + gx0) = m;
        }
    };

    stageA(z0 - 2); stageA(z0 - 1); stageA(z0); stageA(z0 + 1);
    __syncthreads();
    eplane(z0 - 1);
    eplane(z0);
    __syncthreads();
    stageA(z0 + 2);
    __syncthreads();

    for (int z = z0; z < z1; ++z) {
        stageA(z + 3);
        eplane(z + 1);
        __syncthreads();
        {
            const float4* e0 = &Es[(z + 8) % 3][0][0];
            const float4* e1 = &Es[(z + 9) % 3][0][0];
            const float4* e2 = &Es[(z + 10) % 3][0][0];
            float4* mm = &Ms[0][0];
            for (int j = tid; j < EJOBS; j += 256)
                mm[j] = max4(max4(e0[j], e1[j]), e2[j]);
        }
        __syncthreads();
        if (tid < UJOBS) {
            int r = tid / (TX / 4);
            int gp = tid - r * (TX / 4);
            int g = gp + 1;
            float4 d = NINF4;
#pragma unroll
            for (int dy = 0; dy < 3; ++dy) {
                float a  = Ms[r + dy][g - 1].w;
                float4 b = Ms[r + dy][g];
                float c  = Ms[r + dy][g + 1].x;
                d = max4(d, win3max(a, b, c));
            }
            float4 av = As[(z + 8) & 3][r + 2][g];
            float4 delta = make_float4(fmaxf(av.x - d.x, 0.0f),
                                       fmaxf(av.y - d.y, 0.0f),
                                       fmaxf(av.z - d.z, 0.0f),
                                       fmaxf(av.w - d.w, 0.0f));
            size_t gi = (size_t)z * ZS + (size_t)(y0 + r) * YS + (x0 + gp * 4);
            float4* sp4 = (float4*)(Sv + gi);
            float4 s = *sp4;
            s.x += fmaxf(delta.x - s.x * delta.x, 0.0f);
            s.y += fmaxf(delta.y - s.y * delta.y, 0.0f);
            s.z += fmaxf(delta.z - s.z * delta.z, 0.0f);
            s.w += fmaxf(delta.w - s.w * delta.w, 0.0f);
            *sp4 = s;
        }
        __syncthreads();
    }
}

// ---------------- double-round kernel, v2 (row-aligned b128 + shfl) --------
__global__ __launch_bounds__(256, 3) void fused2_kernel(const float* __restrict__ A,
                                                        float* __restrict__ E,
                                                        float* __restrict__ skel) {
    __shared__ float4 As[3][RA][NGP];
    __shared__ float4 E1s[3][RE1][NGP];
    __shared__ float4 E2s[3][RE2][NGP];
    __shared__ float4 M1s[RE2][NGP];
    __shared__ float4 M2s[RE2][NGP];

    const int tid = threadIdx.x;
    const int lr = tid >> 4;
    const int c  = tid & 15;
    const int cc = (c < 14) ? c : 13;
    const int x0 = blockIdx.x * TX;
    const int y0 = blockIdx.y * TY;
    const int v  = blockIdx.z >> 2;
    const int z0 = (blockIdx.z & 3) * ZCH;
    const int z1 = z0 + ZCH;

    const float* Av = A + (size_t)v * VOL;
    float* Ev = E + (size_t)v * VOL;
    float* Sv = skel + (size_t)v * VOL;

    const float4 PINF4 = make_float4(INFINITY, INFINITY, INFINITY, INFINITY);
    const float4 NINF4 = make_float4(-INFINITY, -INFINITY, -INFINITY, -INFINITY);

    float4 Areg0, Areg1;

    auto loadA = [&](int z) {
        if (z < 0 || z >= NZ) { Areg0 = PINF4; Areg1 = PINF4; return; }
        const float* P = Av + (size_t)z * ZS;
        {
            int gy = y0 - 3 + lr;
            int gx0 = x0 - 4 + 4 * c;
            float4 val = PINF4;
            if (c < 14 && gy >= 0 && gy < NY && gx0 >= 0 && gx0 < NX)
                val = *(const float4*)(P + gy * YS + gx0);
            Areg0 = val;
        }
        {
            int r = 16 + lr;
            int gy = y0 - 3 + r;
            int gx0 = x0 - 4 + 4 * c;
            float4 val = PINF4;
            if (r < RA && c < 14 && gy >= 0 && gy < NY && gx0 >= 0 && gx0 < NX)
                val = *(const float4*)(P + gy * YS + gx0);
            Areg1 = val;
        }
    };
    auto writeA = [&](int z) {
        int s = (z + 9) % 3;
        if (c < 14) {
            As[s][lr][c] = Areg0;
            int r1 = 16 + lr;
            if (r1 < RA) As[s][r1][c] = Areg1;
        }
    };

    auto eplane1 = [&](int z) {
        if (z < 0 || z >= NZ) return;
        const int sc = (z + 9) % 3, sm = (z + 8) % 3, sp = (z + 10) % 3;
#pragma unroll
        for (int rb = 0; rb < RE1; rb += 16) {
            int r = rb + lr;
            int rr = (r < RE1) ? r : (RE1 - 1);
            int ar = rr + 1;
            float4 cen = As[sc][ar][cc];
            float4 ylo = As[sc][ar - 1][cc];
            float4 yhi = As[sc][ar + 1][cc];
            float4 zlo = As[sm][ar][cc];
            float4 zhi = As[sp][ar][cc];
            float lw = __shfl_up(cen.w, 1);
            float rx = __shfl_down(cen.x, 1);
            if (c == 0)  lw = INFINITY;
            if (c == 13) rx = INFINITY;
            float4 m = min4(cen, make_float4(lw, cen.x, cen.y, cen.z));
            m = min4(m, make_float4(cen.y, cen.z, cen.w, rx));
            m = min4(m, min4(ylo, yhi));
            m = min4(m, min4(zlo, zhi));
            int gy = y0 - 2 + r;
            int gx0 = x0 - 4 + 4 * c;
            if (gy < 0 || gy >= NY || gx0 < 0 || gx0 >= NX) m = PINF4;
            if (r < RE1 && c < 14) E1s[sc][r][c] = m;
        }
    };

    auto eplane2 = [&](int z, bool wr) {
        if (z < 0 || z >= NZ) return;
        const int sc = (z + 9) % 3, sm = (z + 8) % 3, sp = (z + 10) % 3;
        const bool hm = (z - 1 >= 0), hp = (z + 1 < NZ);
#pragma unroll
        for (int rb = 0; rb < RE2; rb += 16) {
            int r = rb + lr;
            int rr = (r < RE2) ? r : (RE2 - 1);
            int er = rr + 1;
            float4 cen = E1s[sc][er][cc];
            float4 ylo = E1s[sc][er - 1][cc];
            float4 yhi = E1s[sc][er + 1][cc];
            float4 zlo = hm ? E1s[sm][er][cc] : PINF4;
            float4 zhi = hp ? E1s[sp][er][cc] : PINF4;
            float lw = __shfl_up(cen.w, 1);
            float rx = __shfl_down(cen.x, 1);
            if (c == 0)  lw = INFINITY;
            if (c == 13) rx = INFINITY;
            float4 m = min4(cen, make_float4(lw, cen.x, cen.y, cen.z));
            m = min4(m, make_float4(cen.y, cen.z, cen.w, rx));
            m = min4(m, min4(ylo, yhi));
            m = min4(m, min4(zlo, zhi));
            int gy = y0 - 1 + r;
            int gx0 = x0 - 4 + 4 * c;
            if (gy < 0 || gy >= NY || gx0 < 0 || gx0 >= NX) m = PINF4;
            if (r < RE2 && c < 14) {
                E2s[sc][r][c] = m;
                if (wr && r >= 1 && r <= TY && c >= 1 && c <= 12)
                    *(float4*)(Ev + (size_t)z * ZS + gy * YS + gx0) = m;
            }
        }
    };

    auto m1fill = [&](int z) {
        const bool hm = (z - 1 >= 0), hp = (z + 1 < NZ);
        const int s0 = (z + 8) % 3, s1 = (z + 9) % 3, s2 = (z + 10) % 3;
#pragma unroll
        for (int rb = 0; rb < RE2; rb += 16) {
            int r = rb + lr;
            int rr = (r < RE2) ? r : (RE2 - 1);
            int er = rr + 1;
            float4 m = E1s[s1][er][cc];
            if (hm) m = max4(m, E1s[s0][er][cc]);
            if (hp) m = max4(m, E1s[s2][er][cc]);
            int gy = y0 - 1 + r;
            int gx0 = x0 - 4 + 4 * c;
            if (gy < 0 || gy >= NY || gx0 < 0 || gx0 >= NX) m = NINF4;
            if (r < RE2 && c < 14) M1s[r][c] = m;
        }
    };

    auto m2fill = [&](int z) {
        const bool h0 = (z - 1 >= 0), h2 = (z + 1 < NZ);
        const int s0 = (z + 8) % 3, s1 = (z + 9) % 3, s2 = (z + 10) % 3;
#pragma unroll
        for (int rb = 0; rb < RE2; rb += 16) {
            int r = rb + lr;
            int rr = (r < RE2) ? r : (RE2 - 1);
            float4 m = E2s[s1][rr][cc];
            if (h0) m = max4(m, E2s[s0][rr][cc]);
            if (h2) m = max4(m, E2s[s2][rr][cc]);
            int gy = y0 - 1 + r;
            int gx0 = x0 - 4 + 4 * c;
            if (gy < 0 || gy >= NY || gx0 < 0 || gx0 >= NX) m = NINF4;
            if (r < RE2 && c < 14) M2s[r][c] = m;
        }
    };

    const bool uact = (c >= 1 && c <= 12);
    float4 sprev = make_float4(0.f, 0.f, 0.f, 0.f);
    float4 scur  = sprev;
    float4 sreg  = sprev;

    // ---- prologue ----
    loadA(z0 - 3); writeA(z0 - 3);
    loadA(z0 - 2); writeA(z0 - 2);
    loadA(z0 - 1); writeA(z0 - 1);
    __syncthreads();
    eplane1(z0 - 2);
    __syncthreads();
    loadA(z0); writeA(z0);
    __syncthreads();
    eplane1(z0 - 1);
    __syncthreads();
    loadA(z0 + 1); writeA(z0 + 1);
    __syncthreads();
    eplane1(z0);
    __syncthreads();
    eplane2(z0 - 1, false);
    loadA(z0 + 2);
    __syncthreads();

    // ---- main loop ----
    for (int z = z0; z <= z1; ++z) {
        /* P0: commit staged A(z+2); issue skel(z) read */
        writeA(z + 2);
        if (z < z1 && uact)
            sreg = *(const float4*)(Sv + (size_t)z * ZS +
                                    (size_t)(y0 + lr) * YS + x0 + 4 * (c - 1));
        __syncthreads();
        /* P2: E1(z+1); prefetch A(z+3) under it */
        eplane1(z + 1);
        if (z < z1) loadA(z + 3);
        __syncthreads();
        /* P3: E2(z) (+global write), M1(z) */
        eplane2(z, z < z1);
        if (z < z1) m1fill(z);
        __syncthreads();
        /* P4: update1(z) -> scur ; M2(z-1) */
        if (z < z1) {
            float4 m0 = M1s[lr][cc];
            float4 m1 = M1s[lr + 1][cc];
            float4 m2 = M1s[lr + 2][cc];
            float lw0 = __shfl_up(m0.w, 1), rx0 = __shfl_down(m0.x, 1);
            float lw1 = __shfl_up(m1.w, 1), rx1 = __shfl_down(m1.x, 1);
            float lw2 = __shfl_up(m2.w, 1), rx2 = __shfl_down(m2.x, 1);
            if (uact) {
                float4 d = win3max(lw0, m0, rx0);
                d = max4(d, win3max(lw1, m1, rx1));
                d = max4(d, win3max(lw2, m2, rx2));
                float4 a = As[(z + 9) % 3][lr + 3][c];
                float4 s = sreg;
                float dd;
                dd = fmaxf(a.x - d.x, 0.f); s.x += fmaxf(dd - s.x * dd, 0.f);
                dd = fmaxf(a.y - d.y, 0.f); s.y += fmaxf(dd - s.y * dd, 0.f);
                dd = fmaxf(a.z - d.z, 0.f); s.z += fmaxf(dd - s.z * dd, 0.f);
                dd = fmaxf(a.w - d.w, 0.f); s.w += fmaxf(dd - s.w * dd, 0.f);
                scur = s;
            }
        }
        if (z > z0) m2fill(z - 1);
        __syncthreads();
        /* P5: update2(z-1) with sprev; write skel(z-1) */
        if (z > z0) {
            float4 m0 = M2s[lr][cc];
            float4 m1 = M2s[lr + 1][cc];
            float4 m2 = M2s[lr + 2][cc];
            float lw0 = __shfl_up(m0.w, 1), rx0 = __shfl_down(m0.x, 1);
            float lw1 = __shfl_up(m1.w, 1), rx1 = __shfl_down(m1.x, 1);
            float lw2 = __shfl_up(m2.w, 1), rx2 = __shfl_down(m2.x, 1);
            if (uact) {
                float4 d = win3max(lw0, m0, rx0);
                d = max4(d, win3max(lw1, m1, rx1));
                d = max4(d, win3max(lw2, m2, rx2));
                float4 a = E1s[(z + 8) % 3][lr + 2][c];
                float4 s = sprev;
                float dd;
                dd = fmaxf(a.x - d.x, 0.f); s.x += fmaxf(dd - s.x * dd, 0.f);
                dd = fmaxf(a.y - d.y, 0.f); s.y += fmaxf(dd - s.y * dd, 0.f);
                dd = fmaxf(a.z - d.z, 0.f); s.z += fmaxf(dd - s.z * dd, 0.f);
                dd = fmaxf(a.w - d.w, 0.f); s.w += fmaxf(dd - s.w * dd, 0.f);
                *(float4*)(Sv + (size_t)(z - 1) * ZS + (size_t)(y0 + lr) * YS +
                           x0 + 4 * (c - 1)) = s;
            }
        }
        sprev = scur;
    }
}

__global__ void reduce_kernel(const float* __restrict__ skel,
                              const float* __restrict__ pred,
                              const float* __restrict__ target,
                              double* __restrict__ sums) {
    double acc[4] = {0.0, 0.0, 0.0, 0.0};
    const int stride = gridDim.x * blockDim.x;
    const int t0 = blockIdx.x * blockDim.x + threadIdx.x;
    for (int v = 0; v < NV; ++v) {
        const float* base = (v < 2) ? target : pred;
        const float4* in4 = (const float4*)(base + (size_t)((v & 1) * 2 + 1) * VOL);
        const float4* sk4 = (const float4*)(skel + (size_t)v * VOL);
        float fd = 0.f, fs = 0.f;
        for (int p = t0; p < VOL4; p += stride) {
            float4 s = sk4[p], o = in4[p];
            fd += s.x * o.x + s.y * o.y + s.z * o.z + s.w * o.w;
            fs += s.x + s.y + s.z + s.w;
        }
        if (v < 2) { acc[0] += (double)fd; acc[1] += (double)fs; }
        else       { acc[2] += (double)fd; acc[3] += (double)fs; }
    }
#pragma unroll
    for (int off = 32; off > 0; off >>= 1) {
#pragma unroll
        for (int k = 0; k < 4; ++k) acc[k] += __shfl_down(acc[k], off, 64);
    }
    __shared__ double sm[4][4];
    int lane = threadIdx.x & 63;
    int wid = threadIdx.x >> 6;
    if (lane == 0) {
#pragma unroll
        for (int k = 0; k < 4; ++k) sm[wid][k] = acc[k];
    }
    __syncthreads();
    if (threadIdx.x == 0) {
#pragma unroll
        for (int k = 0; k < 4; ++k) {
            double t = sm[0][k] + sm[1][k] + sm[2][k] + sm[3][k];
            atomicAdd(&sums[k], t);
        }
    }
}

__global__ void final_kernel(const double* __restrict__ sums,
                             float* __restrict__ out) {
    if (threadIdx.x == 0 && blockIdx.x == 0) {
        const double SM = 1e-5;
        double tprec = (sums[0] + SM) / (sums[1] + SM);
        double tsens = (sums[2] + SM) / (sums[3] + SM);
        double cl = 2.0 * tprec * tsens / (tprec + tsens + SM);
        out[0] = (float)(1.0 - cl);
    }
}

extern "C" void kernel_launch(void* const* d_in, const int* in_sizes, int n_in,
                              void* d_out, int out_size, void* d_ws, size_t ws_size,
                              hipStream_t stream) {
    const float* pred = (const float*)d_in[0];
    const float* target = (const float*)d_in[1];
    float* out = (float*)d_out;

    float* cur = (float*)d_ws;
    float* ero = cur + NTOT;
    float* skel = ero + NTOT;
    double* sums = (double*)(skel + NTOT);

    hipMemsetAsync(skel, 0, (size_t)NTOT * sizeof(float), stream);
    hipMemsetAsync(sums, 0, 4 * sizeof(double), stream);

    extract_kernel<<<NTOT4 / 256, 256, 0, stream>>>(pred, target, cur);

    dim3 fgrid(NX / TX, NY / TY, NV * 4);   // 768 blocks = 3/CU

    fused_kernel<<<fgrid, 256, 0, stream>>>(cur, ero, skel);
    float* Abuf = ero;
    float* Ebuf = cur;
    for (int j = 0; j < 25; ++j) {
        fused2_kernel<<<fgrid, 256, 0, stream>>>(Abuf, Ebuf, skel);
        float* tmp = Abuf; Abuf = Ebuf; Ebuf = tmp;
    }

    reduce_kernel<<<2048, 256, 0, stream>>>(skel, pred, target, sums);
    final_kernel<<<1, 64, 0, stream>>>(sums, out);
}

// Round 6
// 2445.938 us; speedup vs baseline: 1.3361x; 1.3361x over previous
//
#include <hip/hip_runtime.h>
#include <math.h>

#define NX 192
#define NY 192
#define NZ 96
#define NV 4
#define VOL (NZ * NY * NX)      /* 3,538,944 */
#define NTOT (NV * VOL)         /* 14,155,776 */
#define VOL4 (VOL / 4)
#define NTOT4 (NTOT / 4)
#define YS NX
#define ZS (NY * NX)

/* ---- single-round kernel geometry (round-3 verified) ---- */
#define TX 48
#define TY 16
#define ZCH 24
#define NG 14
#define AROWS (TY + 4)
#define EROWS (TY + 2)
#define AJOBS (AROWS * NG)
#define EJOBS (EROWS * NG)
#define UJOBS (TY * (TX / 4))

/* ---- double-round kernel geometry (new) ---- */
#define TY2 12
#define ZCH2 32
#define NG2 14
#define R2A 18                   /* A rows: halo 3 */
#define R2E1 16                  /* E1 rows: halo 2 */
#define R2E2 14                  /* E2 rows: halo 1 */

__device__ __forceinline__ float4 min4(float4 a, float4 b) {
    return make_float4(fminf(a.x, b.x), fminf(a.y, b.y),
                       fminf(a.z, b.z), fminf(a.w, b.w));
}
__device__ __forceinline__ float4 max4(float4 a, float4 b) {
    return make_float4(fmaxf(a.x, b.x), fmaxf(a.y, b.y),
                       fmaxf(a.z, b.z), fmaxf(a.w, b.w));
}
// per-element max of 3-windows over cells [a, b.x..b.w, c]
__device__ __forceinline__ float4 win3max(float a, float4 b, float c) {
    return make_float4(fmaxf(fmaxf(a, b.x), b.y),
                       fmaxf(fmaxf(b.x, b.y), b.z),
                       fmaxf(fmaxf(b.y, b.z), b.w),
                       fmaxf(fmaxf(b.z, b.w), c));
}

__global__ void extract_kernel(const float* __restrict__ pred,
                               const float* __restrict__ target,
                               float* __restrict__ cur) {
    int i = blockIdx.x * blockDim.x + threadIdx.x;
    if (i >= NTOT4) return;
    int v = i / VOL4;
    int p = i - v * VOL4;
    int b = v & 1;
    const float4* src = (const float4*)((v < 2) ? pred : target);
    ((float4*)cur)[i] = src[(size_t)(b * 2 + 1) * VOL4 + p];
}

// ---------------- single-round kernel (round 0) — verified ----------------
__global__ __launch_bounds__(256, 3) void fused_kernel(const float* __restrict__ A,
                                                       float* __restrict__ E,
                                                       float* __restrict__ skel) {
    __shared__ float4 As[4][AROWS][NG];
    __shared__ float4 Es[3][EROWS][NG];
    __shared__ float4 Ms[EROWS][NG];

    const int tid = threadIdx.x;
    const int x0 = blockIdx.x * TX;
    const int y0 = blockIdx.y * TY;
    const int v  = blockIdx.z >> 2;
    const int z0 = (blockIdx.z & 3) * ZCH;
    const int z1 = z0 + ZCH;

    const float* Av = A + (size_t)v * VOL;
    float* Ev = E + (size_t)v * VOL;
    float* Sv = skel + (size_t)v * VOL;

    const float4 PINF4 = make_float4(INFINITY, INFINITY, INFINITY, INFINITY);
    const float4 NINF4 = make_float4(-INFINITY, -INFINITY, -INFINITY, -INFINITY);

    auto stageA = [&](int z) {
        int slot = (z + 8) & 3;
        float4* dst = &As[slot][0][0];
        if (z < 0 || z >= NZ) {
            for (int j = tid; j < AJOBS; j += 256) dst[j] = PINF4;
        } else {
            const float* P = Av + (size_t)z * ZS;
            for (int j = tid; j < AJOBS; j += 256) {
                int r = j / NG, g = j - r * NG;
                int gy = y0 - 2 + r;
                int gx0 = x0 - 4 + 4 * g;
                float4 val = PINF4;
                if (gy >= 0 && gy < NY && gx0 >= 0 && gx0 < NX)
                    val = *(const float4*)(P + gy * YS + gx0);
                dst[j] = val;
            }
        }
    };

    auto eplane = [&](int z) {
        int es = (z + 9) % 3;
        float4* dst = &Es[es][0][0];
        if (z < 0 || z >= NZ) {
            for (int j = tid; j < EJOBS; j += 256) dst[j] = NINF4;
            return;
        }
        const int sc = (z + 8) & 3;
        const int sm = (z + 7) & 3;
        const int sp = (z + 9) & 3;
        const bool wr = (z >= z0 && z < z1);
        for (int j = tid; j < EJOBS; j += 256) {
            int r = j / NG, g = j - r * NG;
            float4 c  = As[sc][r + 1][g];
            float4 yl = As[sc][r][g];
            float4 yh = As[sc][r + 2][g];
            float4 zl = As[sm][r + 1][g];
            float4 zh = As[sp][r + 1][g];
            float pw = (g > 0)      ? As[sc][r + 1][g - 1].w : INFINITY;
            float nx = (g < NG - 1) ? As[sc][r + 1][g + 1].x : INFINITY;
            float4 xl = make_float4(pw, c.x, c.y, c.z);
            float4 xr = make_float4(c.y, c.z, c.w, nx);
            float4 m = min4(c, xl);
            m = min4(m, xr);
            m = min4(m, yl);
            m = min4(m, yh);
            m = min4(m, zl);
            m = min4(m, zh);
            int gy = y0 - 1 + r;
            int gx0 = x0 - 4 + 4 * g;
            if (gy < 0 || gy >= NY || gx0 < 0 || gx0 >= NX) m = NINF4;
            dst[j] = m;
            if (wr && r >= 1 && r <= TY && g >= 1 && g <= NG - 2)
                *(float4*)(Ev + (size_t)z * ZS + gy * YS + gx0) = m;
        }
    };

    stageA(z0 - 2); stageA(z0 - 1); stageA(z0); stageA(z0 + 1);
    __syncthreads();
    eplane(z0 - 1);
    eplane(z0);
    __syncthreads();
    stageA(z0 + 2);
    __syncthreads();

    for (int z = z0; z < z1; ++z) {
        stageA(z + 3);
        eplane(z + 1);
        __syncthreads();
        {
            const float4* e0 = &Es[(z + 8) % 3][0][0];
            const float4* e1 = &Es[(z + 9) % 3][0][0];
            const float4* e2 = &Es[(z + 10) % 3][0][0];
            float4* mm = &Ms[0][0];
            for (int j = tid; j < EJOBS; j += 256)
                mm[j] = max4(max4(e0[j], e1[j]), e2[j]);
        }
        __syncthreads();
        if (tid < UJOBS) {
            int r = tid / (TX / 4);
            int gp = tid - r * (TX / 4);
            int g = gp + 1;
            float4 d = NINF4;
#pragma unroll
            for (int dy = 0; dy < 3; ++dy) {
                float a  = Ms[r + dy][g - 1].w;
                float4 b = Ms[r + dy][g];
                float c  = Ms[r + dy][g + 1].x;
                d = max4(d, win3max(a, b, c));
            }
            float4 av = As[(z + 8) & 3][r + 2][g];
            float4 delta = make_float4(fmaxf(av.x - d.x, 0.0f),
                                       fmaxf(av.y - d.y, 0.0f),
                                       fmaxf(av.z - d.z, 0.0f),
                                       fmaxf(av.w - d.w, 0.0f));
            size_t gi = (size_t)z * ZS + (size_t)(y0 + r) * YS + (x0 + gp * 4);
            float4* sp4 = (float4*)(Sv + gi);
            float4 s = *sp4;
            s.x += fmaxf(delta.x - s.x * delta.x, 0.0f);
            s.y += fmaxf(delta.y - s.y * delta.y, 0.0f);
            s.z += fmaxf(delta.z - s.z * delta.z, 0.0f);
            s.w += fmaxf(delta.w - s.w * delta.w, 0.0f);
            *sp4 = s;
        }
        __syncthreads();
    }
}

// ---------------- double-round kernel v3: skewed pipeline, 1 barrier/plane --
// Step z computes: E1(z+1)=erode(A), E2(z-1)=erode(E1), upd1(z-1) [A vs
// dilate(E1), s' to regs], upd2(z-3) [E1 vs dilate(E2), skel write].
// All stages read only previous-step LDS state -> single __syncthreads.
// Pads: As/E1s store +inf outside volume (erode pad); E2s stores -inf
// (dilate pad); upd1 substitutes -inf per z-slot / y-row / x-edge.
__global__ __launch_bounds__(256, 3) void fused2_kernel(const float* __restrict__ A,
                                                        float* __restrict__ E,
                                                        float* __restrict__ skel) {
    __shared__ float4 As[5][R2A][NG2];
    __shared__ float4 E1s[5][R2E1][NG2];
    __shared__ float4 E2s[4][R2E2][NG2];

    const int tid = threadIdx.x;
    const int lr  = tid >> 4;               /* row lane 0..15 */
    const int c   = tid & 15;               /* col group 0..15 (0..13 real) */
    const int cc  = (c < 14) ? c : 13;
    const int sr  = tid / 14;               /* stage row 0..18 (252 active) */
    const int sg  = tid - sr * 14;

    const int x0 = blockIdx.x * TX;
    const int y0 = blockIdx.y * TY2;
    const int v  = blockIdx.z / 3;
    const int ch = blockIdx.z % 3;
    const int z0 = ch * ZCH2;
    const int z1 = z0 + ZCH2;

    const float* Av = A + (size_t)v * VOL;
    float*       Ev = E + (size_t)v * VOL;
    float*       Sv = skel + (size_t)v * VOL;

    const float4 PINF4 = make_float4(INFINITY, INFINITY, INFINITY, INFINITY);
    const float4 NINF4 = make_float4(-INFINITY, -INFINITY, -INFINITY, -INFINITY);
    const float4 ZERO4 = make_float4(0.f, 0.f, 0.f, 0.f);

    const bool xlo = (x0 == 0);
    const bool xhi = (x0 + TX == NX);

    const int  gys  = y0 - 3 + sr;
    const int  gxs  = x0 - 4 + 4 * sg;
    const bool stIn = (sr < R2A) && (gys >= 0) && (gys < NY) &&
                      (gxs >= 0) && (gxs < NX);

    const int  gx   = x0 - 4 + 4 * c;
    const bool gxin = (c < 14) && (gx >= 0) && (gx < NX);
    const int  gyu  = y0 + lr - 1;          /* update-cell row */
    const bool uAct = (lr >= 1 && lr <= 12 && c >= 1 && c <= 12);

    auto stageLoad = [&](int za) -> float4 {
        float4 val = PINF4;
        if (stIn && za >= 0 && za < NZ)
            val = *(const float4*)(Av + (size_t)za * ZS + gys * YS + gxs);
        return val;
    };
    auto stageWrite = [&](int za, float4 val) {
        if (sr < R2A) As[(za + 5) % 5][sr][sg] = val;
    };

    auto e1compute = [&](int zp) {          /* E1 plane zp, rows 0..15 */
        const int s_c = (zp + 5) % 5;
        const int s_m = (zp + 4) % 5;
        const int s_p = (zp + 6) % 5;
        const bool hp = (zp + 1 < NZ);
        const int ar = lr + 1;
        float4 cen = As[s_c][ar][cc];
        float4 ylo = As[s_c][ar - 1][cc];
        float4 yhi = As[s_c][ar + 1][cc];
        float4 zlo = As[s_m][ar][cc];
        float4 zhi = hp ? As[s_p][ar][cc] : PINF4;
        float lw = __shfl_up(cen.w, 1);
        float rx = __shfl_down(cen.x, 1);
        if (c == 0) lw = INFINITY;
        float4 m = min4(cen, make_float4(lw, cen.x, cen.y, cen.z));
        m = min4(m, make_float4(cen.y, cen.z, cen.w, rx));
        m = min4(m, min4(ylo, yhi));
        m = min4(m, min4(zlo, zhi));
        const int gy = y0 - 2 + lr;
        if (zp < 0 || gy < 0 || gy >= NY || !gxin) m = PINF4;
        if (c < 14) E1s[s_c][lr][c] = m;
    };

    // ---- prologue: A(z0-3..z0+2), E1(z0-2..z0) ----
    stageWrite(z0 - 3, stageLoad(z0 - 3));
    stageWrite(z0 - 2, stageLoad(z0 - 2));
    stageWrite(z0 - 1, stageLoad(z0 - 1));
    stageWrite(z0,     stageLoad(z0));
    stageWrite(z0 + 1, stageLoad(z0 + 1));
    __syncthreads();
    e1compute(z0 - 2);
    e1compute(z0 - 1);
    __syncthreads();
    stageWrite(z0 + 2, stageLoad(z0 + 2));
    e1compute(z0);
    __syncthreads();

    float4 skA = ZERO4, sq1 = ZERO4, sq2 = ZERO4;

    // ---- main loop: one barrier per step ----
    for (int z = z0; z <= z1 + 2; ++z) {
        /* issue global loads early: next A plane + skel for plane z */
        const bool doStage = (z <= z1 - 1);
        float4 stv = doStage ? stageLoad(z + 3) : PINF4;
        float4 skN = ZERO4;
        if (z < z1 && uAct)
            skN = *(const float4*)(Sv + (size_t)z * ZS + gyu * YS + gx);

        /* E1(z+1) */
        if (z + 1 <= z1 + 1 && z + 1 < NZ) e1compute(z + 1);

        /* merged E2(p) + upd1(p), p = z-1 */
        const int p = z - 1;
        const bool doE2 = (p >= 0) && (p <= z1) && (p < NZ);
        const bool doU1 = (p >= z0) && (p < z1);
        float4 spnew = ZERO4;
        if (doE2 || doU1) {
            const int s0 = (p + 4) % 5;     /* E1 plane p-1 */
            const int s1 = (p + 5) % 5;     /* E1 plane p   */
            const int s2 = (p + 6) % 5;     /* E1 plane p+1 */
            const bool zok0 = (p - 1 >= 0);
            const bool zok2 = (p + 1 < NZ);
            const int r = (lr < R2E2) ? lr : (R2E2 - 1);
            float4 e00 = E1s[s0][r][cc], e01 = E1s[s0][r + 1][cc], e02 = E1s[s0][r + 2][cc];
            float4 e10 = E1s[s1][r][cc], e11 = E1s[s1][r + 1][cc], e12 = E1s[s1][r + 2][cc];
            float4 e20 = E1s[s2][r][cc], e21 = E1s[s2][r + 1][cc], e22 = E1s[s2][r + 2][cc];

            /* ---- E2 erode (plane p, row gy = y0-1+lr) ---- */
            {
                float4 zhiE = zok2 ? e21 : PINF4;   /* stale slot guard */
                float lwE = __shfl_up(e11.w, 1);
                float rxE = __shfl_down(e11.x, 1);
                if (c == 0) lwE = INFINITY;
                float4 m2 = min4(e11, make_float4(lwE, e11.x, e11.y, e11.z));
                m2 = min4(m2, make_float4(e11.y, e11.z, e11.w, rxE));
                m2 = min4(m2, min4(e10, e12));
                m2 = min4(m2, min4(e01, zhiE));
                const int gyE = y0 - 1 + lr;
                bool oob = (gyE < 0) || (gyE >= NY) || !gxin;
                float4 m2st = oob ? NINF4 : m2;
                if (lr < R2E2 && c < 14) {
                    E2s[(p + 4) % 4][lr][c] = m2st;
                    if (p >= z0 && p < z1 && lr >= 1 && lr <= 12 && c >= 1 && c <= 12)
                        *(float4*)(Ev + (size_t)p * ZS + gyE * YS + gx) = m2;
                }
            }

            /* ---- upd1: delta = relu(A(p) - dilate(E1)(p)) at (gyu, gx) ---- */
            if (doU1) {
                float4 d00 = zok0 ? e00 : NINF4;
                float4 d01 = zok0 ? e01 : NINF4;
                float4 d02 = zok0 ? e02 : NINF4;
                float4 d20 = zok2 ? e20 : NINF4;
                float4 d21 = zok2 ? e21 : NINF4;
                float4 d22 = zok2 ? e22 : NINF4;
                bool oy0 = (y0 - 2 + r < 0) || (y0 - 2 + r >= NY);
                bool oy1 = (y0 - 1 + r < 0) || (y0 - 1 + r >= NY);
                bool oy2 = (y0 + r >= NY);
                float4 zm0 = oy0 ? NINF4 : max4(max4(d00, e10), d20);
                float4 zm1 = oy1 ? NINF4 : max4(max4(d01, e11), d21);
                float4 zm2 = oy2 ? NINF4 : max4(max4(d02, e12), d22);
                float lw0 = __shfl_up(zm0.w, 1), rx0 = __shfl_down(zm0.x, 1);
                float lw1 = __shfl_up(zm1.w, 1), rx1 = __shfl_down(zm1.x, 1);
                float lw2 = __shfl_up(zm2.w, 1), rx2 = __shfl_down(zm2.x, 1);
                if (xlo && c == 1)  { lw0 = -INFINITY; lw1 = -INFINITY; lw2 = -INFINITY; }
                if (xhi && c == 12) { rx0 = -INFINITY; rx1 = -INFINITY; rx2 = -INFINITY; }
                float4 dil = win3max(lw0, zm0, rx0);
                dil = max4(dil, win3max(lw1, zm1, rx1));
                dil = max4(dil, win3max(lw2, zm2, rx2));
                float4 a = As[s1][lr + 2][cc];
                float4 s = skA;
                float dd;
                dd = fmaxf(a.x - dil.x, 0.f); s.x += fmaxf(dd - s.x * dd, 0.f);
                dd = fmaxf(a.y - dil.y, 0.f); s.y += fmaxf(dd - s.y * dd, 0.f);
                dd = fmaxf(a.z - dil.z, 0.f); s.z += fmaxf(dd - s.z * dd, 0.f);
                dd = fmaxf(a.w - dil.w, 0.f); s.w += fmaxf(dd - s.w * dd, 0.f);
                spnew = s;
            }
        }

        /* ---- upd2(q): delta = relu(E1(q) - dilate(E2)(q)), q = z-3 ---- */
        const int q = z - 3;
        if (q >= z0 && q < z1) {
            const int t0s = (q + 3) % 4;
            const int t1s = (q + 4) % 4;
            const int t2s = (q + 5) % 4;
            const bool qok0 = (q - 1 >= 0);
            const bool qok2 = (q + 1 < NZ);
            const int rb = (lr >= 1) ? ((lr <= 12) ? lr - 1 : 11) : 0;
            float4 f00 = E2s[t0s][rb][cc], f01 = E2s[t0s][rb + 1][cc], f02 = E2s[t0s][rb + 2][cc];
            float4 f10 = E2s[t1s][rb][cc], f11 = E2s[t1s][rb + 1][cc], f12 = E2s[t1s][rb + 2][cc];
            float4 f20 = E2s[t2s][rb][cc], f21 = E2s[t2s][rb + 1][cc], f22 = E2s[t2s][rb + 2][cc];
            if (!qok0) { f00 = NINF4; f01 = NINF4; f02 = NINF4; }
            if (!qok2) { f20 = NINF4; f21 = NINF4; f22 = NINF4; }
            float4 zq0 = max4(max4(f00, f10), f20);
            float4 zq1 = max4(max4(f01, f11), f21);
            float4 zq2 = max4(max4(f02, f12), f22);
            float lw0 = __shfl_up(zq0.w, 1), rx0 = __shfl_down(zq0.x, 1);
            float lw1 = __shfl_up(zq1.w, 1), rx1 = __shfl_down(zq1.x, 1);
            float lw2 = __shfl_up(zq2.w, 1), rx2 = __shfl_down(zq2.x, 1);
            /* E2s stores -inf pads: no x/y overrides needed */
            float4 dil = win3max(lw0, zq0, rx0);
            dil = max4(dil, win3max(lw1, zq1, rx1));
            dil = max4(dil, win3max(lw2, zq2, rx2));
            const int ra = (lr + 1 < R2E1) ? lr + 1 : (R2E1 - 1);
            float4 a = E1s[(q + 5) % 5][ra][cc];
            float4 s = sq2;
            float dd;
            dd = fmaxf(a.x - dil.x, 0.f); s.x += fmaxf(dd - s.x * dd, 0.f);
            dd = fmaxf(a.y - dil.y, 0.f); s.y += fmaxf(dd - s.y * dd, 0.f);
            dd = fmaxf(a.z - dil.z, 0.f); s.z += fmaxf(dd - s.z * dd, 0.f);
            dd = fmaxf(a.w - dil.w, 0.f); s.w += fmaxf(dd - s.w * dd, 0.f);
            if (uAct)
                *(float4*)(Sv + (size_t)q * ZS + gyu * YS + gx) = s;
        }

        /* commit staged A plane (slot disjoint from all phase readers) */
        if (doStage) stageWrite(z + 3, stv);

        __syncthreads();
        sq2 = sq1; sq1 = spnew; skA = skN;
    }
}

__global__ void reduce_kernel(const float* __restrict__ skel,
                              const float* __restrict__ pred,
                              const float* __restrict__ target,
                              double* __restrict__ sums) {
    double acc[4] = {0.0, 0.0, 0.0, 0.0};
    const int stride = gridDim.x * blockDim.x;
    const int t0 = blockIdx.x * blockDim.x + threadIdx.x;
    for (int v = 0; v < NV; ++v) {
        const float* base = (v < 2) ? target : pred;
        const float4* in4 = (const float4*)(base + (size_t)((v & 1) * 2 + 1) * VOL);
        const float4* sk4 = (const float4*)(skel + (size_t)v * VOL);
        float fd = 0.f, fs = 0.f;
        for (int p = t0; p < VOL4; p += stride) {
            float4 s = sk4[p], o = in4[p];
            fd += s.x * o.x + s.y * o.y + s.z * o.z + s.w * o.w;
            fs += s.x + s.y + s.z + s.w;
        }
        if (v < 2) { acc[0] += (double)fd; acc[1] += (double)fs; }
        else       { acc[2] += (double)fd; acc[3] += (double)fs; }
    }
#pragma unroll
    for (int off = 32; off > 0; off >>= 1) {
#pragma unroll
        for (int k = 0; k < 4; ++k) acc[k] += __shfl_down(acc[k], off, 64);
    }
    __shared__ double sm[4][4];
    int lane = threadIdx.x & 63;
    int wid = threadIdx.x >> 6;
    if (lane == 0) {
#pragma unroll
        for (int k = 0; k < 4; ++k) sm[wid][k] = acc[k];
    }
    __syncthreads();
    if (threadIdx.x == 0) {
#pragma unroll
        for (int k = 0; k < 4; ++k) {
            double t = sm[0][k] + sm[1][k] + sm[2][k] + sm[3][k];
            atomicAdd(&sums[k], t);
        }
    }
}

__global__ void final_kernel(const double* __restrict__ sums,
                             float* __restrict__ out) {
    if (threadIdx.x == 0 && blockIdx.x == 0) {
        const double SM = 1e-5;
        double tprec = (sums[0] + SM) / (sums[1] + SM);
        double tsens = (sums[2] + SM) / (sums[3] + SM);
        double cl = 2.0 * tprec * tsens / (tprec + tsens + SM);
        out[0] = (float)(1.0 - cl);
    }
}

extern "C" void kernel_launch(void* const* d_in, const int* in_sizes, int n_in,
                              void* d_out, int out_size, void* d_ws, size_t ws_size,
                              hipStream_t stream) {
    const float* pred = (const float*)d_in[0];
    const float* target = (const float*)d_in[1];
    float* out = (float*)d_out;

    float* cur = (float*)d_ws;
    float* ero = cur + NTOT;
    float* skel = ero + NTOT;
    double* sums = (double*)(skel + NTOT);

    hipMemsetAsync(skel, 0, (size_t)NTOT * sizeof(float), stream);
    hipMemsetAsync(sums, 0, 4 * sizeof(double), stream);

    extract_kernel<<<NTOT4 / 256, 256, 0, stream>>>(pred, target, cur);

    dim3 fgrid(NX / TX, NY / TY, NV * 4);    // single: 4 x 12 x 16
    dim3 dgrid(NX / TX, NY / TY2, NV * 3);   // double: 4 x 16 x 12 = 768 = 3/CU

    // round 0 (single), then 25 double-round launches: 1 + 25*2 = 51 rounds
    fused_kernel<<<fgrid, 256, 0, stream>>>(cur, ero, skel);
    float* Abuf = ero;
    float* Ebuf = cur;
    for (int j = 0; j < 25; ++j) {
        fused2_kernel<<<dgrid, 256, 0, stream>>>(Abuf, Ebuf, skel);
        float* tmp = Abuf; Abuf = Ebuf; Ebuf = tmp;
    }

    reduce_kernel<<<2048, 256, 0, stream>>>(skel, pred, target, sums);
    final_kernel<<<1, 64, 0, stream>>>(sums, out);
}